// Round 11
// baseline (462.540 us; speedup 1.0000x reference)
//
#include <hip/hip_runtime.h>
#include <stdint.h>
#include <math.h>

typedef unsigned short u16;
typedef __attribute__((ext_vector_type(8))) short short8;
typedef __attribute__((ext_vector_type(4))) float f32x4;

__device__ __forceinline__ float bf2f(u16 u){
  union { unsigned int i; float f; } v; v.i = ((unsigned int)u) << 16; return v.f;
}
__device__ __forceinline__ u16 f2bf(float f){
  union { float f; unsigned int i; } v; v.f = f;
  return (u16)((v.i + 0x7FFFu + ((v.i >> 16) & 1u)) >> 16);
}

// ---------------- LayerNorm + x->bf16 (one row per block, R3 exact) ---------
__global__ void ln_prep(const float* __restrict__ x, const float* __restrict__ g,
                        const float* __restrict__ bta, u16* __restrict__ h,
                        u16* __restrict__ xb, float* __restrict__ loss){
  if (blockIdx.x == 0 && threadIdx.x == 0) loss[0] = 0.f;
  int row = blockIdx.x, tid = threadIdx.x;
  const float4* xr = (const float4*)(x + (size_t)row * 1024);
  float4 v = xr[tid];
  float s  = v.x + v.y + v.z + v.w;
  float s2 = v.x*v.x + v.y*v.y + v.z*v.z + v.w*v.w;
  #pragma unroll
  for (int o = 32; o > 0; o >>= 1){ s += __shfl_down(s, o); s2 += __shfl_down(s2, o); }
  __shared__ float red[8];
  if ((tid & 63) == 0){ red[tid >> 6] = s; red[4 + (tid >> 6)] = s2; }
  __syncthreads();
  float ts = red[0]+red[1]+red[2]+red[3];
  float t2 = red[4]+red[5]+red[6]+red[7];
  float mu   = ts * (1.0f/1024.0f);
  float var  = t2 * (1.0f/1024.0f) - mu*mu;
  float rstd = rsqrtf(var + 1e-5f);
  float4 gg = ((const float4*)g)[tid];
  float4 bb = ((const float4*)bta)[tid];
  ushort4 hv, xv;
  hv.x = f2bf((v.x-mu)*rstd*gg.x + bb.x);
  hv.y = f2bf((v.y-mu)*rstd*gg.y + bb.y);
  hv.z = f2bf((v.z-mu)*rstd*gg.z + bb.z);
  hv.w = f2bf((v.w-mu)*rstd*gg.w + bb.w);
  xv.x = f2bf(v.x); xv.y = f2bf(v.y); xv.z = f2bf(v.z); xv.w = f2bf(v.w);
  ((ushort4*)h )[(size_t)row*256 + tid] = hv;
  ((ushort4*)xb)[(size_t)row*256 + tid] = xv;
}

// ---------------- fp32 -> bf16 weight conversion (5 matrices, R3 exact) -----
__global__ void conv5(const float* __restrict__ a, const float* __restrict__ b,
                      const float* __restrict__ c, const float* __restrict__ d,
                      const float* __restrict__ e,
                      u16* oa, u16* ob, u16* oc, u16* od, u16* oe){
  int sel = blockIdx.y;
  const float* s = sel==0?a : sel==1?b : sel==2?c : sel==3?d : e;
  u16* o = sel==0?oa : sel==1?ob : sel==2?oc : sel==3?od : oe;
  int i = blockIdx.x*256 + threadIdx.x;   // 262144 float4's
  float4 v = ((const float4*)s)[i];
  ushort4 r; r.x=f2bf(v.x); r.y=f2bf(v.y); r.z=f2bf(v.z); r.w=f2bf(v.w);
  ((ushort4*)o)[i] = r;
}

// --------- WeffT[d][e] = W0[e][d] + sum_r A[e][r]*B[r][d] (R3 exact) --------
__global__ void weff_k(const float* __restrict__ W0, const float* __restrict__ Ai,
                       const float* __restrict__ Bi, u16* __restrict__ Wet){
  __shared__ float tile[32][33];
  int d0 = blockIdx.x*32, e0 = blockIdx.y*32;
  int tid = threadIdx.x;
  int lr = tid >> 5, lc = tid & 31;
  #pragma unroll
  for (int s = 0; s < 4; ++s){
    int e = e0 + s*8 + lr, d = d0 + lc;
    float v = W0[(size_t)e*1024 + d];
    #pragma unroll
    for (int r = 0; r < 8; ++r) v += Ai[e*8 + r] * Bi[(size_t)r*1024 + d];
    tile[s*8 + lr][lc] = v;
  }
  __syncthreads();
  #pragma unroll
  for (int s = 0; s < 4; ++s){
    int d = d0 + s*8 + lr, e = e0 + lc;
    Wet[(size_t)d*1024 + e] = f2bf(tile[lc][s*8 + lr]);
  }
}

// =====================================================================
// 256x256 MFMA GEMM (round-3 verified: 140us, MfmaUtil 44.8%, 0 confl).
// 8 waves (2Mx4N), K sliced at 32, 4-slot LDS ring (128 KiB),
// stage-ahead 3 slices, counted vmcnt(8), XOR bank swizzle,
// ONE barrier / zero explicit lgkm waits per slice (free-running).
// EPI: 0 = bf16 store; 1 = layerscale+residual fp32 store;
//      2 = bf16 store + FUSED scan1 (per-chunk grad sums + loss) —
//          each 128-row chunk lies in one tile; wave wm owns one chunk;
//          quad lanes hold its 128 rows for a fixed col -> 2 shfl_xor
//          give the full chunk sum; one direct part store, no atomics.
// =====================================================================
#define VMW(N)  asm volatile("s_waitcnt vmcnt(" #N ")" ::: "memory")
#define SBAR    __builtin_amdgcn_s_barrier()
#define SCHED0  __builtin_amdgcn_sched_barrier(0)

template<int EPI>
__device__ __forceinline__ void gemm256_body(const u16* __restrict__ A, const u16* __restrict__ Bm,
    u16* __restrict__ Cb, float* __restrict__ Cf, const float* __restrict__ lsg,
    const float* __restrict__ xres, const u16* __restrict__ Vv,
    float* __restrict__ part, float* __restrict__ loss, int mblk, int nblk)
{
  __shared__ u16 As[4][8192];
  __shared__ u16 Bs[4][8192];
  const int tid  = threadIdx.x;
  const int lane = tid & 63;
  const int w    = tid >> 6;            // 0..7
  const int wm = w >> 2, wn = w & 3;    // 2 x 4 wave grid
  const int l15 = lane & 15, quad = lane >> 4;
  const int m0 = mblk * 256, n0 = nblk * 256;

  // ---- staging: linear LDS dest, inverse-swizzled global source ----
  const int sl   = (lane & 7) ^ (lane >> 3);
  const int srow = 2*(w*8 + (lane >> 3)) + (sl >> 2);
  const int scol = (sl & 3) * 8;
  const u16* gA = A  + (size_t)(m0 + srow)*1024 + scol;
  const u16* gB = Bm + (size_t)(n0 + srow)*1024 + scol;
  const int ldsOff = w * 512;           // elems; second half adds 4096

  // ---- swizzled read addresses (elems) ----
  const int phys8 = (((((l15 & 1) << 2) | quad) ^ (l15 >> 1))) * 8;
  const int rdA = (wm*64 + (l15 >> 1))*64 + phys8;
  const int rdB = (wn*32 + (l15 >> 1))*64 + phys8;

  f32x4 acc[8][4] = {};

#define SA(T) do{ const int _ss=(T)&3; const size_t _k=(size_t)(T)*32; \
    __builtin_amdgcn_global_load_lds((const __attribute__((address_space(1))) unsigned int*)(gA + _k), \
        (__attribute__((address_space(3))) unsigned int*)(&As[_ss][ldsOff]), 16, 0, 0); \
    __builtin_amdgcn_global_load_lds((const __attribute__((address_space(1))) unsigned int*)(gA + _k + 131072), \
        (__attribute__((address_space(3))) unsigned int*)(&As[_ss][ldsOff + 4096]), 16, 0, 0); \
  }while(0)
#define SB(T) do{ const int _ss=(T)&3; const size_t _k=(size_t)(T)*32; \
    __builtin_amdgcn_global_load_lds((const __attribute__((address_space(1))) unsigned int*)(gB + _k), \
        (__attribute__((address_space(3))) unsigned int*)(&Bs[_ss][ldsOff]), 16, 0, 0); \
    __builtin_amdgcn_global_load_lds((const __attribute__((address_space(1))) unsigned int*)(gB + _k + 131072), \
        (__attribute__((address_space(3))) unsigned int*)(&Bs[_ss][ldsOff + 4096]), 16, 0, 0); \
  }while(0)

#define SLICE(T, VMOP, DS) do{ \
    VMOP; \
    SCHED0; SBAR; SCHED0; \
    if (DS){ SA((T)+3); SB((T)+3); } \
    const int _s = (T) & 3; \
    const u16* _as = &As[_s][0]; \
    const u16* _bs = &Bs[_s][0]; \
    short8 afv[8], bfv[4]; \
    _Pragma("unroll") \
    for (int _j = 0; _j < 4; ++_j) bfv[_j] = *(const short8*)(_bs + rdB + _j*512); \
    _Pragma("unroll") \
    for (int _i = 0; _i < 8; ++_i) afv[_i] = *(const short8*)(_as + rdA + _i*512); \
    _Pragma("unroll") \
    for (int _i = 0; _i < 8; ++_i){ \
      _Pragma("unroll") \
      for (int _j = 0; _j < 4; ++_j) \
        acc[_i][_j] = __builtin_amdgcn_mfma_f32_16x16x32_bf16(afv[_i], bfv[_j], acc[_i][_j], 0, 0, 0); \
    } \
  }while(0)

  // prologue: 3 slices in flight
  SA(0); SB(0); SA(1); SB(1); SA(2); SB(2);

  #pragma unroll 1
  for (int t = 0; t < 28; t += 4){
    SLICE(t+0, VMW(8), 1);
    SLICE(t+1, VMW(8), 1);
    SLICE(t+2, VMW(8), 1);
    SLICE(t+3, VMW(8), 1);
  }
  SLICE(28, VMW(8), 1);   // stages slice 31 (last)
  SLICE(29, VMW(8), 0);   // outstanding {29,30,31}=12 -> 8 => 29 landed
  SLICE(30, VMW(4), 0);   // outstanding {30,31}=8 -> 4    => 30 landed
  SLICE(31, VMW(0), 0);   // outstanding {31}=4 -> 0       => 31 landed
#undef SLICE
#undef SA
#undef SB

  // ---- epilogue: C/D layout col=lane&15, row=quad*4+r (verified) ----
  const int rbase = quad * 4;
  if (EPI == 0){
    #pragma unroll
    for (int i = 0; i < 8; ++i){
      int row = m0 + wm*128 + i*16 + rbase;
      #pragma unroll
      for (int j = 0; j < 4; ++j){
        int col = n0 + wn*64 + j*16 + l15;
        #pragma unroll
        for (int r = 0; r < 4; ++r)
          Cb[(size_t)(row + r)*1024 + col] = f2bf(acc[i][j][r]);
      }
    }
  } else if (EPI == 1){
    float lsv[4];
    #pragma unroll
    for (int j = 0; j < 4; ++j) lsv[j] = lsg[n0 + wn*64 + j*16 + l15];
    #pragma unroll
    for (int i = 0; i < 8; ++i){
      int row = m0 + wm*128 + i*16 + rbase;
      #pragma unroll
      for (int j = 0; j < 4; ++j){
        int col = n0 + wn*64 + j*16 + l15;
        #pragma unroll
        for (int r = 0; r < 4; ++r){
          size_t idx = (size_t)(row + r)*1024 + col;
          Cf[idx] = acc[i][j][r] * lsv[j] + xres[idx];
        }
      }
    }
  } else {
    // EPI == 2: y0 bf16 store + fused scan1 (A == Kb, so K[row][col] = A[idx])
    float g0=0.f, g1=0.f, g2=0.f, g3=0.f, ls=0.f;
    #pragma unroll
    for (int i = 0; i < 8; ++i){
      int row = m0 + wm*128 + i*16 + rbase;
      #pragma unroll
      for (int j = 0; j < 4; ++j){
        int col = n0 + wn*64 + j*16 + l15;
        #pragma unroll
        for (int r = 0; r < 4; ++r){
          size_t idx = (size_t)(row + r)*1024 + col;
          u16 yb = f2bf(acc[i][j][r]);
          Cb[idx] = yb;
          float e = bf2f(yb) - bf2f(Vv[idx]);
          float kv = bf2f(A[idx]);
          ls += e*e;
          float ge = kv*e;
          if (j == 0) g0 += ge; else if (j == 1) g1 += ge;
          else if (j == 2) g2 += ge; else g3 += ge;
        }
      }
    }
    // quad lanes hold the 4 row-subsets of this wave's 128-row chunk
    g0 += __shfl_xor(g0, 16); g0 += __shfl_xor(g0, 32);
    g1 += __shfl_xor(g1, 16); g1 += __shfl_xor(g1, 32);
    g2 += __shfl_xor(g2, 16); g2 += __shfl_xor(g2, 32);
    g3 += __shfl_xor(g3, 16); g3 += __shfl_xor(g3, 32);
    float gw = (quad == 0) ? g0 : (quad == 1) ? g1 : (quad == 2) ? g2 : g3;
    int rowc = m0 + wm*128;
    int bb   = rowc >> 12;              // /4096
    int ch   = (rowc & 4095) >> 7;      // %4096 /128
    int colq = n0 + wn*64 + quad*16 + l15;
    part[((size_t)(bb*32 + ch))*1024 + colq] = gw;
    // loss: wave reduce then one atomic per wave
    #pragma unroll
    for (int o = 32; o > 0; o >>= 1) ls += __shfl_down(ls, o);
    if (lane == 0) atomicAdd(loss, ls);
  }
}

// fused Q/K/V/Gate GEMM: 1024 blocks; XCD-swizzled, A-panel-major layout
__global__ __launch_bounds__(512, 2) void gemm_qkvg(
    const u16* __restrict__ h, const u16* __restrict__ xb,
    const u16* __restrict__ Wqb, const u16* __restrict__ Wkb,
    const u16* __restrict__ Wvb, const u16* __restrict__ Wgb,
    u16* __restrict__ Qb, u16* __restrict__ Kb,
    u16* __restrict__ Vb, u16* __restrict__ Gb){
  int bid = blockIdx.x;                       // 1024 = 8 XCD chunks of 128
  int swz = (bid & 7) * 128 + (bid >> 3);     // bijective (1024 % 8 == 0)
  int mblk = swz >> 4;                        // 64 m-blocks; 8 per XCD chunk
  int rem  = swz & 15;
  int sel  = rem >> 2, nblk = rem & 3;
  const u16* A  = (sel == 3) ? xb : h;
  const u16* Bm = sel==0?Wqb : sel==1?Wkb : sel==2?Wvb : Wgb;
  u16* Out      = sel==0?Qb  : sel==1?Kb  : sel==2?Vb  : Gb;
  gemm256_body<0>(A, Bm, Out, nullptr, nullptr, nullptr, nullptr, nullptr, nullptr, mblk, nblk);
}

// y0 GEMM with fused scan1: A = Kb, emits y0 (bf16), part sums, loss
__global__ __launch_bounds__(512, 2) void gemm_y0scan(
    const u16* __restrict__ Kb, const u16* __restrict__ Wet,
    u16* __restrict__ Y0, const u16* __restrict__ Vb,
    float* __restrict__ part, float* __restrict__ loss){
  int bid = blockIdx.x;                       // 256
  int swz = (bid & 7) * 32 + (bid >> 3);
  gemm256_body<2>(Kb, Wet, Y0, nullptr, nullptr, nullptr, Vb, part, loss, swz >> 2, swz & 3);
}

__global__ __launch_bounds__(512, 2) void gemm_final(
    const u16* __restrict__ A, const u16* __restrict__ Bm,
    float* __restrict__ C, const float* __restrict__ lsg,
    const float* __restrict__ xres){
  int bid = blockIdx.x;                       // 256
  int swz = (bid & 7) * 32 + (bid >> 3);
  gemm256_body<1>(A, Bm, nullptr, C, lsg, xres, nullptr, nullptr, nullptr, swz >> 2, swz & 3);
}

// -------- scan pass 2: out_pre = (y0 - Q*lr*shift*pos_scale)*sigmoid(G) ------
// (round-3 exact form)
__global__ void scan2(const u16* __restrict__ Kb, const u16* __restrict__ Vb,
                      const u16* __restrict__ Yb, const u16* __restrict__ Qb,
                      const u16* __restrict__ Gb, const float* __restrict__ part,
                      const float* __restrict__ llr, u16* __restrict__ OutPre){
  int tid = threadIdx.x;
  int c = blockIdx.x*256 + tid;
  int ch = blockIdx.y, b = blockIdx.z;
  float run = 0.f;
  for (int j = 0; j < ch; ++j) run += part[((size_t)(b*32 + j))*1024 + c];
  float lrc = fminf(expf(llr[c]), 1.0f);
  size_t base = ((size_t)b*4096 + (size_t)ch*128)*1024 + c;
  #pragma unroll 4
  for (int t = 0; t < 128; ++t){
    size_t idx = base + (size_t)t*1024;
    float kv = bf2f(Kb[idx]), vv = bf2f(Vb[idx]), yv = bf2f(Yb[idx]);
    float qv = bf2f(Qb[idx]), gl = bf2f(Gb[idx]);
    float e = yv - vv;
    int tg = ch*128 + t + 1;
    float ps = 1.0f/(1.0f + 0.1f*logf((float)tg));
    float gate = 1.0f/(1.0f + expf(-gl));
    float o = (yv - qv*lrc*run*ps) * gate;
    OutPre[idx] = f2bf(o);     // same buffer as Qb: read-before-write per element
    run += kv*e;
  }
}

__global__ void finloss(const float* __restrict__ loss, float* __restrict__ o){
  o[0] = loss[0] * (1.0f/16777216.0f);
}

extern "C" void kernel_launch(void* const* d_in, const int* in_sizes, int n_in,
                              void* d_out, int out_size, void* d_ws, size_t ws_size,
                              hipStream_t stream){
  const float* x   = (const float*)d_in[0];
  const float* W0  = (const float*)d_in[1];
  const float* Ai  = (const float*)d_in[2];
  const float* Bi  = (const float*)d_in[3];
  const float* llr = (const float*)d_in[4];
  const float* Wq  = (const float*)d_in[5];
  const float* Wk  = (const float*)d_in[6];
  const float* Wv  = (const float*)d_in[7];
  const float* Wo  = (const float*)d_in[8];
  const float* Wg  = (const float*)d_in[9];
  const float* lng = (const float*)d_in[10];
  const float* lnb = (const float*)d_in[11];
  const float* lsg = (const float*)d_in[12];
  float* out = (float*)d_out;

  const size_t TOK = 16384, CC = 1024;
  char* p = (char*)d_ws;
  float* loss = (float*)p; p += 256;
  u16* h   = (u16*)p; p += TOK*CC*2;   // reused as y0 after GEMM1
  u16* xb  = (u16*)p; p += TOK*CC*2;
  u16* Qb  = (u16*)p; p += TOK*CC*2;   // reused as out_pre in scan2
  u16* Kb  = (u16*)p; p += TOK*CC*2;
  u16* Vb  = (u16*)p; p += TOK*CC*2;
  u16* Gb  = (u16*)p; p += TOK*CC*2;
  u16* Wqb = (u16*)p; p += CC*CC*2;
  u16* Wkb = (u16*)p; p += CC*CC*2;
  u16* Wvb = (u16*)p; p += CC*CC*2;
  u16* Wgb = (u16*)p; p += CC*CC*2;
  u16* Wob = (u16*)p; p += CC*CC*2;
  u16* Wet = (u16*)p; p += CC*CC*2;
  float* part = (float*)p; p += (size_t)4*32*1024*4;   // 512 KB (32 chunks)

  ln_prep<<<16384, 256, 0, stream>>>(x, lng, lnb, h, xb, loss);
  conv5<<<dim3(1024, 5), 256, 0, stream>>>(Wq, Wk, Wv, Wg, Wo, Wqb, Wkb, Wvb, Wgb, Wob);
  weff_k<<<dim3(32, 32), 256, 0, stream>>>(W0, Ai, Bi, Wet);
  gemm_qkvg<<<1024, 512, 0, stream>>>(h, xb, Wqb, Wkb, Wvb, Wgb, Qb, Kb, Vb, Gb);
  gemm_y0scan<<<256, 512, 0, stream>>>(Kb, Wet, h, Vb, part, loss);   // y0 + scan1
  scan2<<<dim3(4, 32, 4), 256, 0, stream>>>(Kb, Vb, h, Qb, Gb, part, llr, Qb);
  gemm_final<<<256, 512, 0, stream>>>(Qb, Wob, out, lsg, x);
  finloss<<<1, 1, 0, stream>>>(loss, out + 16777216);
}

// Round 12
// 441.250 us; speedup vs baseline: 1.0482x; 1.0482x over previous
//
#include <hip/hip_runtime.h>
#include <stdint.h>
#include <math.h>

typedef unsigned short u16;
typedef __attribute__((ext_vector_type(8))) short short8;
typedef __attribute__((ext_vector_type(4))) float f32x4;

__device__ __forceinline__ float bf2f(u16 u){
  union { unsigned int i; float f; } v; v.i = ((unsigned int)u) << 16; return v.f;
}
__device__ __forceinline__ u16 f2bf(float f){
  union { float f; unsigned int i; } v; v.f = f;
  return (u16)((v.i + 0x7FFFu + ((v.i >> 16) & 1u)) >> 16);
}

// ---------------- LayerNorm + x->bf16 (one WAVE per row, no barriers) -------
__global__ void ln_prep(const float* __restrict__ x, const float* __restrict__ g,
                        const float* __restrict__ bta, u16* __restrict__ h,
                        u16* __restrict__ xb, float* __restrict__ loss){
  int tid = threadIdx.x, wid = tid >> 6, lane = tid & 63;
  if (blockIdx.x == 0 && tid == 0) loss[0] = 0.f;
  int row = blockIdx.x * 4 + wid;
  const float4* xr = (const float4*)(x + (size_t)row * 1024);
  float4 v[4]; float s = 0.f, s2 = 0.f;
  #pragma unroll
  for (int i = 0; i < 4; ++i){
    v[i] = xr[i*64 + lane];
    s  += v[i].x + v[i].y + v[i].z + v[i].w;
    s2 += v[i].x*v[i].x + v[i].y*v[i].y + v[i].z*v[i].z + v[i].w*v[i].w;
  }
  #pragma unroll
  for (int o = 1; o < 64; o <<= 1){ s += __shfl_xor(s, o); s2 += __shfl_xor(s2, o); }
  float mu   = s * (1.0f/1024.0f);
  float var  = s2 * (1.0f/1024.0f) - mu*mu;
  float rstd = rsqrtf(var + 1e-5f);
  #pragma unroll
  for (int i = 0; i < 4; ++i){
    float4 gg = ((const float4*)g)[i*64 + lane];
    float4 bb = ((const float4*)bta)[i*64 + lane];
    ushort4 hv, xv;
    hv.x = f2bf((v[i].x-mu)*rstd*gg.x + bb.x);
    hv.y = f2bf((v[i].y-mu)*rstd*gg.y + bb.y);
    hv.z = f2bf((v[i].z-mu)*rstd*gg.z + bb.z);
    hv.w = f2bf((v[i].w-mu)*rstd*gg.w + bb.w);
    xv.x = f2bf(v[i].x); xv.y = f2bf(v[i].y); xv.z = f2bf(v[i].z); xv.w = f2bf(v[i].w);
    ((ushort4*)h )[(size_t)row*256 + i*64 + lane] = hv;
    ((ushort4*)xb)[(size_t)row*256 + i*64 + lane] = xv;
  }
}

// ------- fp32 -> bf16 weight conversion (5 matrices) + fused weff (y==5) ----
__global__ void conv5(const float* __restrict__ a, const float* __restrict__ b,
                      const float* __restrict__ c, const float* __restrict__ d,
                      const float* __restrict__ e,
                      const float* __restrict__ W0, const float* __restrict__ Ai,
                      const float* __restrict__ Bi,
                      u16* oa, u16* ob, u16* oc, u16* od, u16* oe,
                      u16* __restrict__ Wet){
  __shared__ float tile[32][33];
  int sel = blockIdx.y;
  int tid = threadIdx.x;
  if (sel == 5){
    // WeffT[d][e] = W0[e][d] + sum_r A[e][r]*B[r][d], bf16 out
    int d0 = (blockIdx.x & 31)*32, e0 = (blockIdx.x >> 5)*32;
    int lr = tid >> 5, lc = tid & 31;
    #pragma unroll
    for (int s = 0; s < 4; ++s){
      int ee = e0 + s*8 + lr, dd = d0 + lc;
      float v = W0[(size_t)ee*1024 + dd];
      #pragma unroll
      for (int r = 0; r < 8; ++r) v += Ai[ee*8 + r] * Bi[(size_t)r*1024 + dd];
      tile[s*8 + lr][lc] = v;
    }
    __syncthreads();
    #pragma unroll
    for (int s = 0; s < 4; ++s){
      int dd = d0 + s*8 + lr, ee = e0 + lc;
      Wet[(size_t)dd*1024 + ee] = f2bf(tile[lc][s*8 + lr]);
    }
    return;
  }
  const float* s = sel==0?a : sel==1?b : sel==2?c : sel==3?d : e;
  u16* o = sel==0?oa : sel==1?ob : sel==2?oc : sel==3?od : oe;
  int i = blockIdx.x*256 + tid;   // 262144 float4's
  float4 v = ((const float4*)s)[i];
  ushort4 r; r.x=f2bf(v.x); r.y=f2bf(v.y); r.z=f2bf(v.z); r.w=f2bf(v.w);
  ((ushort4*)o)[i] = r;
}

// =====================================================================
// 256x256 MFMA GEMM (round-3 verified: ~139us, MfmaUtil ~44%, 0 confl).
// 8 waves (2Mx4N), K sliced at 32, 4-slot LDS ring (128 KiB),
// stage-ahead 3 slices, counted vmcnt(8), XOR bank swizzle,
// ONE barrier / zero explicit lgkm waits per slice (free-running).
// EPI: 0 = bf16 store; 1 = layerscale+residual fp32 store;
//      2 = bf16 store + FUSED scan1 (per-chunk grad sums + loss) —
//          each 128-row chunk lies in one tile; wave wm owns one chunk;
//          quad lanes hold its 128 rows for a fixed col -> 2 shfl_xor
//          give the full chunk sum; one direct part store, no atomics.
// =====================================================================
#define VMW(N)  asm volatile("s_waitcnt vmcnt(" #N ")" ::: "memory")
#define SBAR    __builtin_amdgcn_s_barrier()
#define SCHED0  __builtin_amdgcn_sched_barrier(0)

template<int EPI>
__device__ __forceinline__ void gemm256_body(const u16* __restrict__ A, const u16* __restrict__ Bm,
    u16* __restrict__ Cb, float* __restrict__ Cf, const float* __restrict__ lsg,
    const float* __restrict__ xres, const u16* __restrict__ Vv,
    float* __restrict__ part, float* __restrict__ loss, int mblk, int nblk)
{
  __shared__ u16 As[4][8192];
  __shared__ u16 Bs[4][8192];
  const int tid  = threadIdx.x;
  const int lane = tid & 63;
  const int w    = tid >> 6;            // 0..7
  const int wm = w >> 2, wn = w & 3;    // 2 x 4 wave grid
  const int l15 = lane & 15, quad = lane >> 4;
  const int m0 = mblk * 256, n0 = nblk * 256;

  // ---- staging: linear LDS dest, inverse-swizzled global source ----
  const int sl   = (lane & 7) ^ (lane >> 3);
  const int srow = 2*(w*8 + (lane >> 3)) + (sl >> 2);
  const int scol = (sl & 3) * 8;
  const u16* gA = A  + (size_t)(m0 + srow)*1024 + scol;
  const u16* gB = Bm + (size_t)(n0 + srow)*1024 + scol;
  const int ldsOff = w * 512;           // elems; second half adds 4096

  // ---- swizzled read addresses (elems) ----
  const int phys8 = (((((l15 & 1) << 2) | quad) ^ (l15 >> 1))) * 8;
  const int rdA = (wm*64 + (l15 >> 1))*64 + phys8;
  const int rdB = (wn*32 + (l15 >> 1))*64 + phys8;

  f32x4 acc[8][4] = {};

#define SA(T) do{ const int _ss=(T)&3; const size_t _k=(size_t)(T)*32; \
    __builtin_amdgcn_global_load_lds((const __attribute__((address_space(1))) unsigned int*)(gA + _k), \
        (__attribute__((address_space(3))) unsigned int*)(&As[_ss][ldsOff]), 16, 0, 0); \
    __builtin_amdgcn_global_load_lds((const __attribute__((address_space(1))) unsigned int*)(gA + _k + 131072), \
        (__attribute__((address_space(3))) unsigned int*)(&As[_ss][ldsOff + 4096]), 16, 0, 0); \
  }while(0)
#define SB(T) do{ const int _ss=(T)&3; const size_t _k=(size_t)(T)*32; \
    __builtin_amdgcn_global_load_lds((const __attribute__((address_space(1))) unsigned int*)(gB + _k), \
        (__attribute__((address_space(3))) unsigned int*)(&Bs[_ss][ldsOff]), 16, 0, 0); \
    __builtin_amdgcn_global_load_lds((const __attribute__((address_space(1))) unsigned int*)(gB + _k + 131072), \
        (__attribute__((address_space(3))) unsigned int*)(&Bs[_ss][ldsOff + 4096]), 16, 0, 0); \
  }while(0)

#define SLICE(T, VMOP, DS) do{ \
    VMOP; \
    SCHED0; SBAR; SCHED0; \
    if (DS){ SA((T)+3); SB((T)+3); } \
    const int _s = (T) & 3; \
    const u16* _as = &As[_s][0]; \
    const u16* _bs = &Bs[_s][0]; \
    short8 afv[8], bfv[4]; \
    _Pragma("unroll") \
    for (int _j = 0; _j < 4; ++_j) bfv[_j] = *(const short8*)(_bs + rdB + _j*512); \
    _Pragma("unroll") \
    for (int _i = 0; _i < 8; ++_i) afv[_i] = *(const short8*)(_as + rdA + _i*512); \
    _Pragma("unroll") \
    for (int _i = 0; _i < 8; ++_i){ \
      _Pragma("unroll") \
      for (int _j = 0; _j < 4; ++_j) \
        acc[_i][_j] = __builtin_amdgcn_mfma_f32_16x16x32_bf16(afv[_i], bfv[_j], acc[_i][_j], 0, 0, 0); \
    } \
  }while(0)

  // prologue: 3 slices in flight
  SA(0); SB(0); SA(1); SB(1); SA(2); SB(2);

  #pragma unroll 1
  for (int t = 0; t < 28; t += 4){
    SLICE(t+0, VMW(8), 1);
    SLICE(t+1, VMW(8), 1);
    SLICE(t+2, VMW(8), 1);
    SLICE(t+3, VMW(8), 1);
  }
  SLICE(28, VMW(8), 1);   // stages slice 31 (last)
  SLICE(29, VMW(8), 0);   // outstanding {29,30,31}=12 -> 8 => 29 landed
  SLICE(30, VMW(4), 0);   // outstanding {30,31}=8 -> 4    => 30 landed
  SLICE(31, VMW(0), 0);   // outstanding {31}=4 -> 0       => 31 landed
#undef SLICE
#undef SA
#undef SB

  // ---- epilogue: C/D layout col=lane&15, row=quad*4+r (verified) ----
  const int rbase = quad * 4;
  if (EPI == 0){
    #pragma unroll
    for (int i = 0; i < 8; ++i){
      int row = m0 + wm*128 + i*16 + rbase;
      #pragma unroll
      for (int j = 0; j < 4; ++j){
        int col = n0 + wn*64 + j*16 + l15;
        #pragma unroll
        for (int r = 0; r < 4; ++r)
          Cb[(size_t)(row + r)*1024 + col] = f2bf(acc[i][j][r]);
      }
    }
  } else if (EPI == 1){
    float lsv[4];
    #pragma unroll
    for (int j = 0; j < 4; ++j) lsv[j] = lsg[n0 + wn*64 + j*16 + l15];
    #pragma unroll
    for (int i = 0; i < 8; ++i){
      int row = m0 + wm*128 + i*16 + rbase;
      #pragma unroll
      for (int j = 0; j < 4; ++j){
        int col = n0 + wn*64 + j*16 + l15;
        #pragma unroll
        for (int r = 0; r < 4; ++r){
          size_t idx = (size_t)(row + r)*1024 + col;
          Cf[idx] = acc[i][j][r] * lsv[j] + xres[idx];
        }
      }
    }
  } else {
    // EPI == 2: y0 bf16 store + fused scan1 (A == Kb, so K[row][col] = A[idx])
    float g0=0.f, g1=0.f, g2=0.f, g3=0.f, ls=0.f;
    #pragma unroll
    for (int i = 0; i < 8; ++i){
      int row = m0 + wm*128 + i*16 + rbase;
      #pragma unroll
      for (int j = 0; j < 4; ++j){
        int col = n0 + wn*64 + j*16 + l15;
        #pragma unroll
        for (int r = 0; r < 4; ++r){
          size_t idx = (size_t)(row + r)*1024 + col;
          u16 yb = f2bf(acc[i][j][r]);
          Cb[idx] = yb;
          float e = bf2f(yb) - bf2f(Vv[idx]);
          float kv = bf2f(A[idx]);
          ls += e*e;
          float ge = kv*e;
          if (j == 0) g0 += ge; else if (j == 1) g1 += ge;
          else if (j == 2) g2 += ge; else g3 += ge;
        }
      }
    }
    // quad lanes hold the 4 row-subsets of this wave's 128-row chunk
    g0 += __shfl_xor(g0, 16); g0 += __shfl_xor(g0, 32);
    g1 += __shfl_xor(g1, 16); g1 += __shfl_xor(g1, 32);
    g2 += __shfl_xor(g2, 16); g2 += __shfl_xor(g2, 32);
    g3 += __shfl_xor(g3, 16); g3 += __shfl_xor(g3, 32);
    float gw = (quad == 0) ? g0 : (quad == 1) ? g1 : (quad == 2) ? g2 : g3;
    int rowc = m0 + wm*128;
    int bb   = rowc >> 12;              // /4096
    int ch   = (rowc & 4095) >> 7;      // %4096 /128
    int colq = n0 + wn*64 + quad*16 + l15;
    part[((size_t)(bb*32 + ch))*1024 + colq] = gw;
    // loss: wave reduce then one atomic per wave
    #pragma unroll
    for (int o = 32; o > 0; o >>= 1) ls += __shfl_down(ls, o);
    if (lane == 0) atomicAdd(loss, ls);
  }
}

// fused Q/K/V/Gate GEMM: 1024 blocks; XCD-swizzled, A-panel-major layout
__global__ __launch_bounds__(512, 2) void gemm_qkvg(
    const u16* __restrict__ h, const u16* __restrict__ xb,
    const u16* __restrict__ Wqb, const u16* __restrict__ Wkb,
    const u16* __restrict__ Wvb, const u16* __restrict__ Wgb,
    u16* __restrict__ Qb, u16* __restrict__ Kb,
    u16* __restrict__ Vb, u16* __restrict__ Gb){
  int bid = blockIdx.x;                       // 1024 = 8 XCD chunks of 128
  int swz = (bid & 7) * 128 + (bid >> 3);     // bijective (1024 % 8 == 0)
  int mblk = swz >> 4;                        // 64 m-blocks; 8 per XCD chunk
  int rem  = swz & 15;
  int sel  = rem >> 2, nblk = rem & 3;
  const u16* A  = (sel == 3) ? xb : h;
  const u16* Bm = sel==0?Wqb : sel==1?Wkb : sel==2?Wvb : Wgb;
  u16* Out      = sel==0?Qb  : sel==1?Kb  : sel==2?Vb  : Gb;
  gemm256_body<0>(A, Bm, Out, nullptr, nullptr, nullptr, nullptr, nullptr, nullptr, mblk, nblk);
}

// y0 GEMM with fused scan1: A = Kb, emits y0 (bf16), part sums, loss
__global__ __launch_bounds__(512, 2) void gemm_y0scan(
    const u16* __restrict__ Kb, const u16* __restrict__ Wet,
    u16* __restrict__ Y0, const u16* __restrict__ Vb,
    float* __restrict__ part, float* __restrict__ loss){
  int bid = blockIdx.x;                       // 256
  int swz = (bid & 7) * 32 + (bid >> 3);
  gemm256_body<2>(Kb, Wet, Y0, nullptr, nullptr, nullptr, Vb, part, loss, swz >> 2, swz & 3);
}

// gemm_final also emits the scalar loss (gemm_y0scan completed earlier in stream)
__global__ __launch_bounds__(512, 2) void gemm_final(
    const u16* __restrict__ A, const u16* __restrict__ Bm,
    float* __restrict__ C, const float* __restrict__ lsg,
    const float* __restrict__ xres, const float* __restrict__ loss){
  if (blockIdx.x == 0 && threadIdx.x == 0)
    C[16777216] = loss[0] * (1.0f/16777216.0f);
  int bid = blockIdx.x;                       // 256
  int swz = (bid & 7) * 32 + (bid >> 3);
  gemm256_body<1>(A, Bm, nullptr, C, lsg, xres, nullptr, nullptr, nullptr, swz >> 2, swz & 3);
}

// -------- scan pass 2: out_pre = (y0 - Q*lr*shift*pos_scale)*sigmoid(G) ------
// (round-3 exact form)
__global__ void scan2(const u16* __restrict__ Kb, const u16* __restrict__ Vb,
                      const u16* __restrict__ Yb, const u16* __restrict__ Qb,
                      const u16* __restrict__ Gb, const float* __restrict__ part,
                      const float* __restrict__ llr, u16* __restrict__ OutPre){
  int tid = threadIdx.x;
  int c = blockIdx.x*256 + tid;
  int ch = blockIdx.y, b = blockIdx.z;
  float run = 0.f;
  for (int j = 0; j < ch; ++j) run += part[((size_t)(b*32 + j))*1024 + c];
  float lrc = fminf(expf(llr[c]), 1.0f);
  size_t base = ((size_t)b*4096 + (size_t)ch*128)*1024 + c;
  #pragma unroll 4
  for (int t = 0; t < 128; ++t){
    size_t idx = base + (size_t)t*1024;
    float kv = bf2f(Kb[idx]), vv = bf2f(Vb[idx]), yv = bf2f(Yb[idx]);
    float qv = bf2f(Qb[idx]), gl = bf2f(Gb[idx]);
    float e = yv - vv;
    int tg = ch*128 + t + 1;
    float ps = 1.0f/(1.0f + 0.1f*logf((float)tg));
    float gate = 1.0f/(1.0f + expf(-gl));
    float o = (yv - qv*lrc*run*ps) * gate;
    OutPre[idx] = f2bf(o);     // same buffer as Qb: read-before-write per element
    run += kv*e;
  }
}

extern "C" void kernel_launch(void* const* d_in, const int* in_sizes, int n_in,
                              void* d_out, int out_size, void* d_ws, size_t ws_size,
                              hipStream_t stream){
  const float* x   = (const float*)d_in[0];
  const float* W0  = (const float*)d_in[1];
  const float* Ai  = (const float*)d_in[2];
  const float* Bi  = (const float*)d_in[3];
  const float* llr = (const float*)d_in[4];
  const float* Wq  = (const float*)d_in[5];
  const float* Wk  = (const float*)d_in[6];
  const float* Wv  = (const float*)d_in[7];
  const float* Wo  = (const float*)d_in[8];
  const float* Wg  = (const float*)d_in[9];
  const float* lng = (const float*)d_in[10];
  const float* lnb = (const float*)d_in[11];
  const float* lsg = (const float*)d_in[12];
  float* out = (float*)d_out;

  const size_t TOK = 16384, CC = 1024;
  char* p = (char*)d_ws;
  float* loss = (float*)p; p += 256;
  u16* h   = (u16*)p; p += TOK*CC*2;   // reused as y0 after GEMM1
  u16* xb  = (u16*)p; p += TOK*CC*2;
  u16* Qb  = (u16*)p; p += TOK*CC*2;   // reused as out_pre in scan2
  u16* Kb  = (u16*)p; p += TOK*CC*2;
  u16* Vb  = (u16*)p; p += TOK*CC*2;
  u16* Gb  = (u16*)p; p += TOK*CC*2;
  u16* Wqb = (u16*)p; p += CC*CC*2;
  u16* Wkb = (u16*)p; p += CC*CC*2;
  u16* Wvb = (u16*)p; p += CC*CC*2;
  u16* Wgb = (u16*)p; p += CC*CC*2;
  u16* Wob = (u16*)p; p += CC*CC*2;
  u16* Wet = (u16*)p; p += CC*CC*2;
  float* part = (float*)p; p += (size_t)4*32*1024*4;   // 512 KB (32 chunks)

  ln_prep<<<4096, 256, 0, stream>>>(x, lng, lnb, h, xb, loss);
  conv5<<<dim3(1024, 6), 256, 0, stream>>>(Wq, Wk, Wv, Wg, Wo, W0, Ai, Bi,
                                           Wqb, Wkb, Wvb, Wgb, Wob, Wet);
  gemm_qkvg<<<1024, 512, 0, stream>>>(h, xb, Wqb, Wkb, Wvb, Wgb, Qb, Kb, Vb, Gb);
  gemm_y0scan<<<256, 512, 0, stream>>>(Kb, Wet, h, Vb, part, loss);   // y0 + scan1
  scan2<<<dim3(4, 32, 4), 256, 0, stream>>>(Kb, Vb, h, Qb, Gb, part, llr, Qb);
  gemm_final<<<256, 512, 0, stream>>>(Qb, Wob, out, lsg, x, loss);
}